// Round 5
// baseline (517.359 us; speedup 1.0000x reference)
//
#include <hip/hip_runtime.h>

// T=4096, B=8, E=512. Dual EMA (pos/neg split) along T. fp32 in/out.
//   pb = sigmoid(raw_pos_beta[e]); nb = sigmoid(raw_neg_beta[e])
//   mem_p[t] = pb*mem_p[t-1] + max(x,0)*(1-pb)
//   mem_n[t] = nb*mem_n[t-1] + min(x,0)*(1-nb)
//   out[t,b,e] = mem_p + mem_n
//
// SINGLE fused kernel, DEADLOCK-FREE at any residency (round-4 lesson:
// the block0-sweeps/all-wait-block0 cycle needed all 256 blocks resident
// and hung the GPU). New structure is a chunk-ordered pipeline with no
// dependency cycles:
//   - 256 blocks x 1024 threads; block c owns chunk c (16 t-steps).
//   - Every block: local scan -> publish aggregate agg[c] + flag1[c]
//     (UNCONDITIONALLY, before any wait).
//   - Blocks 0..31 (dispatched first), wave 0: sweeper role. Sweeper i owns
//     64 of the 2048 (state x quad-col) lanes and folds aggregates in CHUNK
//     ORDER (groups of 8, poll flag1), writing inclusive carries incl[j]
//     and bumping done2[j/8] (32 sweepers per group => counter reaches 32).
//   - Block c>0 waits only on done2[(c-1)/8], reads incl[c-1], re-reads its
//     x chunk (LLC-resident: 64MB x + 16MB ws << 256MB L3), writes out.
//   Progress argument: completion of block c depends only on aggs of chunks
//   <= c (sweep is chunk-ordered). If the lowest undispatched block is b*,
//   all resident blocks < b* can finish -> CUs free -> b* placed. No cycle.
// No register x-caching (round-1 spill lesson); phase 3 re-reads x.
// ws layout (floats): agg[256][2][4096] | incl[256][2][4096] |
//   flag1[256] u32 | done2[32] u32   (16 MB + 1.2 KB)
// Pre-kernel zeroes the 288 flag words each launch (ws is poisoned).
// Fallback: verified round-0 3-kernel path (135.9us) if ws too small.

#define T_DIM 4096
#define B_DIM 8
#define E_DIM 512
#define CHUNK_L 16
#define NCHUNK (T_DIM / CHUNK_L)   // 256
#define BE (B_DIM * E_DIM)         // 4096
#define NSWEEP 32                  // sweeper blocks (must divide 2048 slots)
#define GRP 8                      // chunks per sweep group
#define NGRP (NCHUNK / GRP)        // 32

__device__ __forceinline__ float sigmoidf_(float x) { return 1.0f / (1.0f + __expf(-x)); }

// --- dispatch 1: zero flag words (ws is poisoned by the harness) ---
__global__ __launch_bounds__(512) void k_zero_flags(unsigned int* __restrict__ flags) {
    int i = threadIdx.x;
    if (i < NCHUNK + NGRP) flags[i] = 0u;
}

// --- dispatch 2: fused chunked scan ---
__global__ __launch_bounds__(1024, 1) void ParallelDLIEMA_17789754541002_kernel(
        const float* __restrict__ x,
        const float* __restrict__ rp,
        const float* __restrict__ rn,
        float* __restrict__ out,
        float* __restrict__ ws) {
    const int c   = blockIdx.x;          // chunk 0..255
    const int tid = threadIdx.x;         // 0..1023
    const int e   = (tid & 127) * 4;     // E/4 = 128 quads
    const int b   = tid >> 7;            // 0..7
    const int col = b * E_DIM + e;       // float index within BE

    float* agg  = ws;                                     // [NCHUNK][2][BE]
    float* incl = ws + 2 * NCHUNK * BE;                   // [NCHUNK][2][BE]
    unsigned int* flag1 = (unsigned int*)(ws + 4 * NCHUNK * BE); // [NCHUNK]
    unsigned int* done2 = flag1 + NCHUNK;                 // [NGRP]

    float4 rp4 = *(const float4*)(rp + e);
    float4 rn4 = *(const float4*)(rn + e);
    float bp[4] = {sigmoidf_(rp4.x), sigmoidf_(rp4.y), sigmoidf_(rp4.z), sigmoidf_(rp4.w)};
    float bn[4] = {sigmoidf_(rn4.x), sigmoidf_(rn4.y), sigmoidf_(rn4.z), sigmoidf_(rn4.w)};

    const int xbase = c * CHUNK_L * BE + col;

    // ---- Phase 1: local dual scan (zero init); no register caching of x.
    float fp[4] = {0.f, 0.f, 0.f, 0.f};
    float fn[4] = {0.f, 0.f, 0.f, 0.f};
    #pragma unroll
    for (int k = 0; k < CHUNK_L; k++) {
        float4 xv = *(const float4*)(x + xbase + k * BE);
        float f[4] = {xv.x, xv.y, xv.z, xv.w};
        #pragma unroll
        for (int j = 0; j < 4; j++) {
            fp[j] = bp[j] * fp[j] + fmaxf(f[j], 0.f) * (1.0f - bp[j]);
            fn[j] = bn[j] * fn[j] + fminf(f[j], 0.f) * (1.0f - bn[j]);
        }
    }

    // ---- Publish aggregate (before ANY wait — pipeline has no cycles).
    *(float4*)(agg + (size_t)(c * 2 + 0) * BE + col) = make_float4(fp[0], fp[1], fp[2], fp[3]);
    *(float4*)(agg + (size_t)(c * 2 + 1) * BE + col) = make_float4(fn[0], fn[1], fn[2], fn[3]);
    __syncthreads();
    if (tid == 0) {
        __threadfence();   // push agg to device scope (L2 writeback cross-XCD)
        __hip_atomic_store(&flag1[c], 1u, __ATOMIC_RELEASE, __HIP_MEMORY_SCOPE_AGENT);
    }

    // ---- Sweeper role: blocks 0..31, wave 0 only. Chunk-ordered fold.
    if (c < NSWEEP && tid < 64) {
        const int slot  = c * 64 + tid;       // 0..2047 = (state, quadcol)
        const int s     = slot >> 10;         // 0 = pos, 1 = neg
        const int q     = slot & 1023;        // quadcol within BE
        const int coff  = q * 4;              // float offset within BE
        const int ebeta = (q & 127) * 4;      // e index (beta depends on e only)

        float4 rb = *(const float4*)((s ? rn : rp) + ebeta);
        float bl[4] = {sigmoidf_(rb.x), sigmoidf_(rb.y), sigmoidf_(rb.z), sigmoidf_(rb.w)};
        #pragma unroll
        for (int j = 0; j < 4; j++) {         // beta^16
            float t = bl[j] * bl[j]; t *= t; t *= t; t *= t; bl[j] = t;
        }

        float cr[4] = {0.f, 0.f, 0.f, 0.f};
        for (int g = 0; g < NGRP; ++g) {
            // wait for aggs of chunks g*8..g*8+7 (usually already published)
            for (;;) {
                unsigned f = __hip_atomic_load(&flag1[g * GRP + (tid & 7)],
                                               __ATOMIC_RELAXED, __HIP_MEMORY_SCOPE_AGENT);
                if (__all(f != 0u)) break;
                __builtin_amdgcn_s_sleep(2);
            }
            __threadfence();   // acquire: agg stores visible to our loads
            #pragma unroll
            for (int u = 0; u < GRP; ++u) {
                const int j = g * GRP + u;
                const float4 a = *(const float4*)(agg + (size_t)(j * 2 + s) * BE + coff);
                cr[0] = bl[0] * cr[0] + a.x;
                cr[1] = bl[1] * cr[1] + a.y;
                cr[2] = bl[2] * cr[2] + a.z;
                cr[3] = bl[3] * cr[3] + a.w;
                *(float4*)(incl + (size_t)(j * 2 + s) * BE + coff) =
                    make_float4(cr[0], cr[1], cr[2], cr[3]);
            }
            __threadfence();   // push incl before counting this group done
            if (tid == 0)
                __hip_atomic_fetch_add(&done2[g], 1u, __ATOMIC_RELEASE, __HIP_MEMORY_SCOPE_AGENT);
        }
    }

    // ---- Wait for exclusive carry (chunk c needs incl[c-1]); c==0 seeds 0.
    float lp[4] = {0.f, 0.f, 0.f, 0.f};
    float ln[4] = {0.f, 0.f, 0.f, 0.f};
    if (c > 0) {
        const int g2 = (c - 1) >> 3;          // group containing chunk c-1
        const int lane = tid & 63;
        unsigned v = 0;
        for (;;) {
            if (lane == 0)
                v = __hip_atomic_load(&done2[g2], __ATOMIC_RELAXED, __HIP_MEMORY_SCOPE_AGENT);
            v = __shfl(v, 0);
            if (v >= (unsigned)NSWEEP) break;
            __builtin_amdgcn_s_sleep(16);
        }
        __threadfence();   // acquire: incl stores visible
        float4 cp = *(const float4*)(incl + (size_t)((c - 1) * 2 + 0) * BE + col);
        float4 cn = *(const float4*)(incl + (size_t)((c - 1) * 2 + 1) * BE + col);
        lp[0] = cp.x; lp[1] = cp.y; lp[2] = cp.z; lp[3] = cp.w;
        ln[0] = cn.x; ln[1] = cn.y; ln[2] = cn.z; ln[3] = cn.w;
    }

    // ---- Phase 3: re-read x (LLC-hit), replay with seed, write out.
    #pragma unroll
    for (int k = 0; k < CHUNK_L; k++) {
        float4 xv = *(const float4*)(x + xbase + k * BE);
        float f[4] = {xv.x, xv.y, xv.z, xv.w};
        float o[4];
        #pragma unroll
        for (int j = 0; j < 4; j++) {
            lp[j] = bp[j] * lp[j] + fmaxf(f[j], 0.f) * (1.0f - bp[j]);
            ln[j] = bn[j] * ln[j] + fminf(f[j], 0.f) * (1.0f - bn[j]);
            o[j] = lp[j] + ln[j];
        }
        *(float4*)(out + xbase + k * BE) = make_float4(o[0], o[1], o[2], o[3]);
    }
}

// ================= fallback: verified round-0 3-kernel path (135.9us) ====

__global__ __launch_bounds__(256) void k1_local(
        const float* __restrict__ x, const float* __restrict__ rp,
        const float* __restrict__ rn, float* __restrict__ out) {
    int gtid = blockIdx.x * 256 + threadIdx.x;
    int e4 = gtid & 127; int b = (gtid >> 7) & 7; int c = gtid >> 10; int e = e4 * 4;
    float4 rp4 = *(const float4*)(rp + e);
    float4 rn4 = *(const float4*)(rn + e);
    float bp[4] = {sigmoidf_(rp4.x), sigmoidf_(rp4.y), sigmoidf_(rp4.z), sigmoidf_(rp4.w)};
    float bn[4] = {sigmoidf_(rn4.x), sigmoidf_(rn4.y), sigmoidf_(rn4.z), sigmoidf_(rn4.w)};
    float fp4[4] = {0.f,0.f,0.f,0.f}, fn4[4] = {0.f,0.f,0.f,0.f};
    int base = c * CHUNK_L * BE + b * E_DIM + e;
    #pragma unroll
    for (int k = 0; k < CHUNK_L; k++) {
        float4 xv = *(const float4*)(x + base + k * BE);
        float f[4] = {xv.x, xv.y, xv.z, xv.w};
        #pragma unroll
        for (int j = 0; j < 4; j++) {
            fp4[j] = bp[j] * fp4[j] + fmaxf(f[j], 0.f) * (1.0f - bp[j]);
            fn4[j] = bn[j] * fn4[j] + fminf(f[j], 0.f) * (1.0f - bn[j]);
        }
    }
    *(float4*)(out + base + 0 * BE) = make_float4(fp4[0], fp4[1], fp4[2], fp4[3]);
    *(float4*)(out + base + 1 * BE) = make_float4(fn4[0], fn4[1], fn4[2], fn4[3]);
}

__global__ __launch_bounds__(256) void k_carry(const float* __restrict__ rp,
                                               const float* __restrict__ rn,
                                               float* __restrict__ out) {
    int gtid = blockIdx.x * 256 + threadIdx.x;
    int e = gtid & 511; int b = (gtid >> 9) & 7; int s = gtid >> 12;
    float beta = sigmoidf_(s ? rn[e] : rp[e]);
    float bl = beta * beta; bl = bl * bl; bl = bl * bl; bl = bl * bl;
    float* p = out + s * BE + b * E_DIM + e;
    float carry = 0.f;
    for (int g = 0; g < NCHUNK / 16; g++) {
        float fv[16];
        #pragma unroll
        for (int u = 0; u < 16; u++) fv[u] = p[(g * 16 + u) * (CHUNK_L * BE)];
        #pragma unroll
        for (int u = 0; u < 16; u++) {
            p[(g * 16 + u) * (CHUNK_L * BE)] = carry;
            carry = bl * carry + fv[u];
        }
    }
}

__global__ __launch_bounds__(256) void k_out(const float* __restrict__ x,
                                             const float* __restrict__ rp,
                                             const float* __restrict__ rn,
                                             float* __restrict__ out) {
    int gtid = blockIdx.x * 256 + threadIdx.x;
    int e4 = gtid & 127; int b = (gtid >> 7) & 7; int c = gtid >> 10; int e = e4 * 4;
    float4 rp4 = *(const float4*)(rp + e);
    float4 rn4 = *(const float4*)(rn + e);
    float bp[4] = {sigmoidf_(rp4.x), sigmoidf_(rp4.y), sigmoidf_(rp4.z), sigmoidf_(rp4.w)};
    float bn[4] = {sigmoidf_(rn4.x), sigmoidf_(rn4.y), sigmoidf_(rn4.z), sigmoidf_(rn4.w)};
    int base = c * CHUNK_L * BE + b * E_DIM + e;
    float4 cp = *(const float4*)(out + base + 0 * BE);
    float4 cn = *(const float4*)(out + base + 1 * BE);
    float lp[4] = {cp.x, cp.y, cp.z, cp.w};
    float ln[4] = {cn.x, cn.y, cn.z, cn.w};
    #pragma unroll
    for (int k = 0; k < CHUNK_L; k++) {
        float4 xv = *(const float4*)(x + base + k * BE);
        float f[4] = {xv.x, xv.y, xv.z, xv.w};
        float o[4];
        #pragma unroll
        for (int j = 0; j < 4; j++) {
            lp[j] = bp[j] * lp[j] + fmaxf(f[j], 0.f) * (1.0f - bp[j]);
            ln[j] = bn[j] * ln[j] + fminf(f[j], 0.f) * (1.0f - bn[j]);
            o[j] = lp[j] + ln[j];
        }
        *(float4*)(out + base + k * BE) = make_float4(o[0], o[1], o[2], o[3]);
    }
}

extern "C" void kernel_launch(void* const* d_in, const int* in_sizes, int n_in,
                              void* d_out, int out_size, void* d_ws, size_t ws_size,
                              hipStream_t stream) {
    const float* x  = (const float*)d_in[0];
    const float* rp = (const float*)d_in[1];
    const float* rn = (const float*)d_in[2];
    float* out = (float*)d_out;

    const size_t need = (size_t)4 * NCHUNK * BE * sizeof(float)      // agg+incl 16MB
                        + (NCHUNK + NGRP) * sizeof(unsigned int);    // flags
    if (d_ws != nullptr && ws_size >= need) {
        float* ws = (float*)d_ws;
        unsigned int* flags = (unsigned int*)(ws + 4 * NCHUNK * BE);
        k_zero_flags<<<1, 512, 0, stream>>>(flags);
        ParallelDLIEMA_17789754541002_kernel<<<NCHUNK, 1024, 0, stream>>>(x, rp, rn, out, ws);
    } else {
        // verified fallback (135.9 us)
        k1_local<<<1024, 256, 0, stream>>>(x, rp, rn, out);
        k_carry<<<32, 256, 0, stream>>>(rp, rn, out);
        k_out<<<1024, 256, 0, stream>>>(x, rp, rn, out);
    }
}

// Round 6
// 129.684 us; speedup vs baseline: 3.9894x; 3.9894x over previous
//
#include <hip/hip_runtime.h>

// T=4096, B=8, E=512. Dual EMA (pos/neg split) along T. fp32 in/out.
//   pb = sigmoid(raw_pos_beta[e]); nb = sigmoid(raw_neg_beta[e])
//   mem_p[t] = pb*mem_p[t-1] + max(x,0)*(1-pb)
//   mem_n[t] = nb*mem_n[t-1] + min(x,0)*(1-nb)
//   out[t,b,e] = mem_p + mem_n
//
// TWO dispatches, ZERO inter-block sync (r1 cooperative=417us, r5 flag
// pipeline=436us kernel: device-scope spin/fence machinery costs 300+us on
// CDNA4 -> abandoned for good).
//   k_agg : chunk c (32 t-steps) aggregates with zero init -> ws (4 MB).
//   k_main: block REDUNDANTLY folds carry = fold_{j<c} (A=beta^32) over
//           agg[j] (coalesced, L2/LLC-resident, avg 64x8KB per block;
//           ~260MB aggregate L2 traffic ~ 8us machine-wide), then re-reads
//           its x chunk (LLC-hit: 64MB x + 4MB agg << 256MB L3) and writes
//           the final output. Redundant-fold replaces the old serial K2
//           dispatch AND one launch gap.
// Measured constant: dur_us carries ~86us of harness poison-fills (2x43us,
// 256MB each) on top of kernel time; baseline trio kernel-sum ~48us ->
// this structure ~34us.
// ws layout: agg[128][2][4096] floats = 4 MB. k_agg fully overwrites agg
// before k_main reads it (stream order) -> poison-safe, no flags needed.
// Fallback: verified round-0 3-kernel path (135.9us) if ws < 4 MB.

#define T_DIM 4096
#define B_DIM 8
#define E_DIM 512
#define CHUNK_L 32
#define NCHUNK (T_DIM / CHUNK_L)   // 128
#define BE (B_DIM * E_DIM)         // 4096

__device__ __forceinline__ float sigmoidf_(float x) { return 1.0f / (1.0f + __expf(-x)); }

// k_agg: 131072 threads; thread = (c, q). 32 strided float4 loads of x.
__global__ __launch_bounds__(256) void k_agg(
        const float* __restrict__ x,
        const float* __restrict__ rp,
        const float* __restrict__ rn,
        float* __restrict__ agg) {
    const int gtid = blockIdx.x * 256 + threadIdx.x;
    const int q = gtid & 1023;          // col-quad 0..1023
    const int c = gtid >> 10;           // chunk 0..127
    const int e = (q & 127) * 4;
    const int b = q >> 7;
    const int col = b * E_DIM + e;

    float4 rp4 = *(const float4*)(rp + e);
    float4 rn4 = *(const float4*)(rn + e);
    float bp[4] = {sigmoidf_(rp4.x), sigmoidf_(rp4.y), sigmoidf_(rp4.z), sigmoidf_(rp4.w)};
    float bn[4] = {sigmoidf_(rn4.x), sigmoidf_(rn4.y), sigmoidf_(rn4.z), sigmoidf_(rn4.w)};

    float fp[4] = {0.f, 0.f, 0.f, 0.f};
    float fn[4] = {0.f, 0.f, 0.f, 0.f};
    const int xbase = c * CHUNK_L * BE + col;
    #pragma unroll
    for (int k = 0; k < CHUNK_L; k++) {
        float4 xv = *(const float4*)(x + xbase + k * BE);
        float f[4] = {xv.x, xv.y, xv.z, xv.w};
        #pragma unroll
        for (int j = 0; j < 4; j++) {
            fp[j] = bp[j] * fp[j] + fmaxf(f[j], 0.f) * (1.0f - bp[j]);
            fn[j] = bn[j] * fn[j] + fminf(f[j], 0.f) * (1.0f - bn[j]);
        }
    }
    *(float4*)(agg + (size_t)(c * 2 + 0) * BE + col) = make_float4(fp[0], fp[1], fp[2], fp[3]);
    *(float4*)(agg + (size_t)(c * 2 + 1) * BE + col) = make_float4(fn[0], fn[1], fn[2], fn[3]);
}

// k_main: same shape. Redundant prefix fold (no sync), then stream chunk.
__global__ __launch_bounds__(256) void ParallelDLIEMA_17789754541002_kernel(
        const float* __restrict__ x,
        const float* __restrict__ rp,
        const float* __restrict__ rn,
        const float* __restrict__ agg,
        float* __restrict__ out) {
    const int gtid = blockIdx.x * 256 + threadIdx.x;
    const int q = gtid & 1023;
    const int c = gtid >> 10;
    const int e = (q & 127) * 4;
    const int b = q >> 7;
    const int col = b * E_DIM + e;

    float4 rp4 = *(const float4*)(rp + e);
    float4 rn4 = *(const float4*)(rn + e);
    float bp[4] = {sigmoidf_(rp4.x), sigmoidf_(rp4.y), sigmoidf_(rp4.z), sigmoidf_(rp4.w)};
    float bn[4] = {sigmoidf_(rn4.x), sigmoidf_(rn4.y), sigmoidf_(rn4.z), sigmoidf_(rn4.w)};

    // beta^32 (five squarings)
    float Ap[4], An[4];
    #pragma unroll
    for (int j = 0; j < 4; j++) {
        float t = bp[j] * bp[j]; t *= t; t *= t; t *= t; t *= t; Ap[j] = t;
        float u = bn[j] * bn[j]; u *= u; u *= u; u *= u; u *= u; An[j] = u;
    }

    // redundant fold: carry into chunk c (ascending j, s = A*s + F_j)
    float sp[4] = {0.f, 0.f, 0.f, 0.f};
    float sn[4] = {0.f, 0.f, 0.f, 0.f};
    #pragma unroll 4
    for (int j = 0; j < c; ++j) {
        float4 ap = *(const float4*)(agg + (size_t)(j * 2 + 0) * BE + col);
        float4 an = *(const float4*)(agg + (size_t)(j * 2 + 1) * BE + col);
        sp[0] = Ap[0] * sp[0] + ap.x;  sn[0] = An[0] * sn[0] + an.x;
        sp[1] = Ap[1] * sp[1] + ap.y;  sn[1] = An[1] * sn[1] + an.y;
        sp[2] = Ap[2] * sp[2] + ap.z;  sn[2] = An[2] * sn[2] + an.z;
        sp[3] = Ap[3] * sp[3] + ap.w;  sn[3] = An[3] * sn[3] + an.w;
    }

    // stream chunk: x (LLC-resident) -> out, seeded with the carry
    const int xbase = c * CHUNK_L * BE + col;
    #pragma unroll
    for (int k = 0; k < CHUNK_L; k++) {
        float4 xv = *(const float4*)(x + xbase + k * BE);
        float f[4] = {xv.x, xv.y, xv.z, xv.w};
        float o[4];
        #pragma unroll
        for (int j = 0; j < 4; j++) {
            sp[j] = bp[j] * sp[j] + fmaxf(f[j], 0.f) * (1.0f - bp[j]);
            sn[j] = bn[j] * sn[j] + fminf(f[j], 0.f) * (1.0f - bn[j]);
            o[j] = sp[j] + sn[j];
        }
        *(float4*)(out + xbase + k * BE) = make_float4(o[0], o[1], o[2], o[3]);
    }
}

// ================= fallback: verified round-0 3-kernel path (135.9us) ====

#define FB_CHUNK_L 16
#define FB_NCHUNK (T_DIM / FB_CHUNK_L)   // 256

__global__ __launch_bounds__(256) void k1_local(
        const float* __restrict__ x, const float* __restrict__ rp,
        const float* __restrict__ rn, float* __restrict__ out) {
    int gtid = blockIdx.x * 256 + threadIdx.x;
    int e4 = gtid & 127; int b = (gtid >> 7) & 7; int c = gtid >> 10; int e = e4 * 4;
    float4 rp4 = *(const float4*)(rp + e);
    float4 rn4 = *(const float4*)(rn + e);
    float bp[4] = {sigmoidf_(rp4.x), sigmoidf_(rp4.y), sigmoidf_(rp4.z), sigmoidf_(rp4.w)};
    float bn[4] = {sigmoidf_(rn4.x), sigmoidf_(rn4.y), sigmoidf_(rn4.z), sigmoidf_(rn4.w)};
    float fp4[4] = {0.f,0.f,0.f,0.f}, fn4[4] = {0.f,0.f,0.f,0.f};
    int base = c * FB_CHUNK_L * BE + b * E_DIM + e;
    #pragma unroll
    for (int k = 0; k < FB_CHUNK_L; k++) {
        float4 xv = *(const float4*)(x + base + k * BE);
        float f[4] = {xv.x, xv.y, xv.z, xv.w};
        #pragma unroll
        for (int j = 0; j < 4; j++) {
            fp4[j] = bp[j] * fp4[j] + fmaxf(f[j], 0.f) * (1.0f - bp[j]);
            fn4[j] = bn[j] * fn4[j] + fminf(f[j], 0.f) * (1.0f - bn[j]);
        }
    }
    *(float4*)(out + base + 0 * BE) = make_float4(fp4[0], fp4[1], fp4[2], fp4[3]);
    *(float4*)(out + base + 1 * BE) = make_float4(fn4[0], fn4[1], fn4[2], fn4[3]);
}

__global__ __launch_bounds__(256) void k_carry(const float* __restrict__ rp,
                                               const float* __restrict__ rn,
                                               float* __restrict__ out) {
    int gtid = blockIdx.x * 256 + threadIdx.x;
    int e = gtid & 511; int b = (gtid >> 9) & 7; int s = gtid >> 12;
    float beta = sigmoidf_(s ? rn[e] : rp[e]);
    float bl = beta * beta; bl = bl * bl; bl = bl * bl; bl = bl * bl;
    float* p = out + s * BE + b * E_DIM + e;
    float carry = 0.f;
    for (int g = 0; g < FB_NCHUNK / 16; g++) {
        float fv[16];
        #pragma unroll
        for (int u = 0; u < 16; u++) fv[u] = p[(g * 16 + u) * (FB_CHUNK_L * BE)];
        #pragma unroll
        for (int u = 0; u < 16; u++) {
            p[(g * 16 + u) * (FB_CHUNK_L * BE)] = carry;
            carry = bl * carry + fv[u];
        }
    }
}

__global__ __launch_bounds__(256) void k_out(const float* __restrict__ x,
                                             const float* __restrict__ rp,
                                             const float* __restrict__ rn,
                                             float* __restrict__ out) {
    int gtid = blockIdx.x * 256 + threadIdx.x;
    int e4 = gtid & 127; int b = (gtid >> 7) & 7; int c = gtid >> 10; int e = e4 * 4;
    float4 rp4 = *(const float4*)(rp + e);
    float4 rn4 = *(const float4*)(rn + e);
    float bp[4] = {sigmoidf_(rp4.x), sigmoidf_(rp4.y), sigmoidf_(rp4.z), sigmoidf_(rp4.w)};
    float bn[4] = {sigmoidf_(rn4.x), sigmoidf_(rn4.y), sigmoidf_(rn4.z), sigmoidf_(rn4.w)};
    int base = c * FB_CHUNK_L * BE + b * E_DIM + e;
    float4 cp = *(const float4*)(out + base + 0 * BE);
    float4 cn = *(const float4*)(out + base + 1 * BE);
    float lp[4] = {cp.x, cp.y, cp.z, cp.w};
    float ln[4] = {cn.x, cn.y, cn.z, cn.w};
    #pragma unroll
    for (int k = 0; k < FB_CHUNK_L; k++) {
        float4 xv = *(const float4*)(x + base + k * BE);
        float f[4] = {xv.x, xv.y, xv.z, xv.w};
        float o[4];
        #pragma unroll
        for (int j = 0; j < 4; j++) {
            lp[j] = bp[j] * lp[j] + fmaxf(f[j], 0.f) * (1.0f - bp[j]);
            ln[j] = bn[j] * ln[j] + fminf(f[j], 0.f) * (1.0f - bn[j]);
            o[j] = lp[j] + ln[j];
        }
        *(float4*)(out + base + k * BE) = make_float4(o[0], o[1], o[2], o[3]);
    }
}

extern "C" void kernel_launch(void* const* d_in, const int* in_sizes, int n_in,
                              void* d_out, int out_size, void* d_ws, size_t ws_size,
                              hipStream_t stream) {
    const float* x  = (const float*)d_in[0];
    const float* rp = (const float*)d_in[1];
    const float* rn = (const float*)d_in[2];
    float* out = (float*)d_out;

    const size_t need = (size_t)2 * NCHUNK * BE * sizeof(float);   // 4 MB
    if (d_ws != nullptr && ws_size >= need) {
        float* agg = (float*)d_ws;
        // 128 chunks * 1024 col-quads = 131072 threads = 512 blocks
        k_agg<<<512, 256, 0, stream>>>(x, rp, rn, agg);
        ParallelDLIEMA_17789754541002_kernel<<<512, 256, 0, stream>>>(x, rp, rn, agg, out);
    } else {
        // verified fallback (135.9 us)
        k1_local<<<1024, 256, 0, stream>>>(x, rp, rn, out);
        k_carry<<<32, 256, 0, stream>>>(rp, rn, out);
        k_out<<<1024, 256, 0, stream>>>(x, rp, rn, out);
    }
}